// Round 10
// baseline (748.421 us; speedup 1.0000x reference)
//
#include <hip/hip_runtime.h>
#include <hip/hip_bf16.h>
#include <math.h>

#define N_NODES 50000
#define M_PAD   50048           // 782 * 64 rows; fc0 uses 1564 * 32
#define E_EDGES 800000
#define IN_DIM  512
#define HDIM    128
#define CDIM    40
#define LAYERS  8
#define NB      196             // scan blocks: ceil(50000/256)

typedef __attribute__((ext_vector_type(8))) short short8;
typedef __attribute__((ext_vector_type(4))) float floatx4;
typedef unsigned short ushort_t;

__device__ inline float bf2f(unsigned short u) {
    return __uint_as_float(((unsigned)u) << 16);
}
__device__ inline unsigned short f2bf(float v) {
    __hip_bfloat16 b = __float2bfloat16(v);
    return *reinterpret_cast<unsigned short*>(&b);
}

// ---------------- CSR build ----------------

__global__ void hist_kernel(const int* __restrict__ dst, int* __restrict__ cnt) {
    int i = blockIdx.x * blockDim.x + threadIdx.x;
    if (i < E_EDGES) atomicAdd(&cnt[dst[i]], 1);
}

__global__ void scanA(const int* __restrict__ cnt, int* __restrict__ bsum) {
    __shared__ int sm[256];
    int t = threadIdx.x, i = blockIdx.x * 256 + t;
    sm[t] = (i < N_NODES) ? cnt[i] : 0;
    __syncthreads();
    for (int d = 128; d > 0; d >>= 1) {
        if (t < d) sm[t] += sm[t + d];
        __syncthreads();
    }
    if (t == 0) bsum[blockIdx.x] = sm[0];
}

__global__ void scanB(const int* __restrict__ bsum, int* __restrict__ boff) {
    __shared__ int sm[256];
    int t = threadIdx.x;
    sm[t] = (t < NB) ? bsum[t] : 0;
    __syncthreads();
    for (int d = 1; d < 256; d <<= 1) {
        int v = (t >= d) ? sm[t - d] : 0;
        __syncthreads();
        sm[t] += v;
        __syncthreads();
    }
    if (t < NB) boff[t] = (t > 0) ? sm[t - 1] : 0;
}

__global__ void scanC(const int* __restrict__ cnt, const int* __restrict__ boff,
                      int* __restrict__ row_start, int* __restrict__ cursor) {
    __shared__ int sm[256];
    int t = threadIdx.x, i = blockIdx.x * 256 + t;
    int v = (i < N_NODES) ? cnt[i] : 0;
    sm[t] = v;
    __syncthreads();
    for (int d = 1; d < 256; d <<= 1) {
        int x = (t >= d) ? sm[t - d] : 0;
        __syncthreads();
        sm[t] += x;
        __syncthreads();
    }
    if (i < N_NODES) {
        int incl = boff[blockIdx.x] + sm[t];
        int excl = incl - v;
        row_start[i] = excl;
        cursor[i]    = excl;
        if (i == N_NODES - 1) row_start[N_NODES] = incl;
    }
}

__global__ void scatter_kernel(const int* __restrict__ ei, const float* __restrict__ normA,
                               int* __restrict__ cursor, int2* __restrict__ perm) {
    int i = blockIdx.x * blockDim.x + threadIdx.x;
    if (i >= E_EDGES) return;
    int d = ei[E_EDGES + i];
    int idx = atomicAdd(&cursor[d], 1);
    perm[idx] = make_int2(ei[i], __float_as_int(normA[i]));
}

// ---------------- weight prep: transpose + bf16 convert ----------------

__global__ void prep_weights(const float* __restrict__ W0, const float* __restrict__ convW,
                             const float* __restrict__ W1,
                             ushort_t* __restrict__ Wt0, ushort_t* __restrict__ WtL,
                             ushort_t* __restrict__ Wt1) {
    int i = blockIdx.x * blockDim.x + threadIdx.x;
    if (i < 128 * 512) {
        int n = i >> 9, k = i & 511;
        Wt0[i] = f2bf(W0[k * HDIM + n]);
        return;
    }
    int j = i - 128 * 512;
    if (j < 8 * 128 * 128) {
        int l = j >> 14, rem = j & 16383, n = rem >> 7, k = rem & 127;
        WtL[j] = f2bf(convW[l * 16384 + k * HDIM + n]);
        return;
    }
    int m = j - 8 * 128 * 128;
    if (m < 48 * 128) {
        int n = m >> 7, k = m & 127;
        Wt1[m] = (n < CDIM) ? f2bf(W1[k * CDIM + n]) : (ushort_t)0;
    }
}

// ---------------- fc0: x = relu(F @ W0 + b0) -> h0b (bf16) ----------------
// Round-9 structure kept: triple-buffer gll staging, counted vmcnt + s_barrier.

__global__ __launch_bounds__(256)
void fc0_mfma(const float* __restrict__ F, const ushort_t* __restrict__ Wt0,
              const float* __restrict__ b0, ushort_t* __restrict__ h0b) {
    __shared__ float sA[3][32 * 128];   // 3 x 16KB
    int t = threadIdx.x;
    int wave = t >> 6, lane = t & 63;
    int quad = lane >> 4, l16 = lane & 15;
    int R0 = blockIdx.x * 32;

    const ushort_t* bbase = Wt0 + (size_t)(wave * 32 + l16) * IN_DIM + quad * 8;

    floatx4 acc[2][2];   // [rowfrag][nt]
#pragma unroll
    for (int rf = 0; rf < 2; rf++)
#pragma unroll
        for (int nt = 0; nt < 2; nt++) acc[rf][nt] = (floatx4){0.f, 0.f, 0.f, 0.f};

    auto stage = [&](int cc, int buf) {
#pragma unroll
        for (int i = 0; i < 4; i++) {
            int X = i * 4096 + wave * 1024 + lane * 16;     // byte in 16KB chunk
            int row = X >> 9;
            int colb = (X & 511) ^ ((row & 7) << 4);
            int gr = R0 + row; if (gr > N_NODES - 1) gr = N_NODES - 1;
            const float* src = F + (size_t)gr * IN_DIM + cc * 128 + (colb >> 2);
            __builtin_amdgcn_global_load_lds(
                (const __attribute__((address_space(1))) unsigned int*)src,
                (__attribute__((address_space(3))) unsigned int*)&sA[buf][i * 1024 + wave * 256],
                16, 0, 0);
        }
    };

    stage(0, 0);
    stage(1, 1);

    int mask = (l16 & 7) << 4;                 // per-lane read swizzle (bytes)
    int ib0 = ((quad << 5) ^ mask) >> 2;       // float offsets within ks-block
    int ib1 = (((quad << 5) | 16) ^ mask) >> 2;

#pragma unroll
    for (int cc = 0; cc < 4; cc++) {
        asm volatile("s_waitcnt vmcnt(4)" ::: "memory");   // chunk cc landed (in-order)
        __builtin_amdgcn_s_barrier();
        __builtin_amdgcn_sched_barrier(0);
        if (cc < 2) stage(cc + 2, (cc + 2) % 3);
        const float* bufp = &sA[cc % 3][0];
        const float* r0p = bufp + l16 * 128;
        const float* r1p = bufp + (l16 + 16) * 128;
#pragma unroll
        for (int k2 = 0; k2 < 4; k2++) {
            int ks = cc * 4 + k2;
            float4 f00 = *(const float4*)(r0p + k2 * 32 + ib0);
            float4 f01 = *(const float4*)(r0p + k2 * 32 + ib1);
            float4 f10 = *(const float4*)(r1p + k2 * 32 + ib0);
            float4 f11 = *(const float4*)(r1p + k2 * 32 + ib1);
            short8 a0, a1;
            a0[0] = (short)f2bf(f00.x); a0[1] = (short)f2bf(f00.y);
            a0[2] = (short)f2bf(f00.z); a0[3] = (short)f2bf(f00.w);
            a0[4] = (short)f2bf(f01.x); a0[5] = (short)f2bf(f01.y);
            a0[6] = (short)f2bf(f01.z); a0[7] = (short)f2bf(f01.w);
            a1[0] = (short)f2bf(f10.x); a1[1] = (short)f2bf(f10.y);
            a1[2] = (short)f2bf(f10.z); a1[3] = (short)f2bf(f10.w);
            a1[4] = (short)f2bf(f11.x); a1[5] = (short)f2bf(f11.y);
            a1[6] = (short)f2bf(f11.z); a1[7] = (short)f2bf(f11.w);
#pragma unroll
            for (int nt = 0; nt < 2; nt++) {
                short8 b = *(const short8*)(bbase + (size_t)nt * 16 * IN_DIM + ks * 32);
                acc[0][nt] = __builtin_amdgcn_mfma_f32_16x16x32_bf16(a0, b, acc[0][nt], 0, 0, 0);
                acc[1][nt] = __builtin_amdgcn_mfma_f32_16x16x32_bf16(a1, b, acc[1][nt], 0, 0, 0);
            }
        }
    }

#pragma unroll
    for (int nt = 0; nt < 2; nt++) {
        int col = wave * 32 + nt * 16 + l16;
        float bias = b0[col];
#pragma unroll
        for (int r = 0; r < 4; r++) {
            int row = R0 + quad * 4 + r;
            float v = acc[0][nt][r] + bias;
            v = v > 0.f ? v : 0.f;
            h0b[(size_t)row * HDIM + col] = f2bf(v);
        }
#pragma unroll
        for (int r = 0; r < 4; r++) {
            int row = R0 + 16 + quad * 4 + r;
            float v = acc[1][nt][r] + bias;
            v = v > 0.f ? v : 0.f;
            h0b[(size_t)row * HDIM + col] = f2bf(v);
        }
    }
}

// -------- fused layer: sup = 0.9*(A x)+0.1*h0 (into LDS); x' = relu(beta*(sup W)+(1-beta)*sup)
// block = 64 rows, 256 thr / 4 waves; 16-lane group owns 4 rows.
// Round-10: rows processed as 2 interleaved PAIRS -- both rows' 8-gather
// batches issue together (16 loads in flight vs 8) and the serial latency
// chain per group is 2 steps, not 4. Static unrolled slots (compile-time
// shfl lanes); dynamic-trip of round-9 reverted (runtime shfl -> bpermute).
// Register budget kept safe: 2x acc[8] + 16 transient short8 (~150-190 VGPR,
// vs round-4's spilling 256).

#define SROW 136   // 128 + 8 pad

__device__ __forceinline__ void spmm_proc32(int2 pa, int2 pb,
                                            const ushort_t* __restrict__ xb,
                                            int sl, float* __restrict__ acc) {
#pragma unroll
    for (int j = 0; j < 16; j += 4) {
        int   a0 = __shfl(pa.x, j + 0, 16), b0 = __shfl(pb.x, j + 0, 16);
        int   a1 = __shfl(pa.x, j + 1, 16), b1 = __shfl(pb.x, j + 1, 16);
        int   a2 = __shfl(pa.x, j + 2, 16), b2 = __shfl(pb.x, j + 2, 16);
        int   a3 = __shfl(pa.x, j + 3, 16), b3 = __shfl(pb.x, j + 3, 16);
        float wa0 = __int_as_float(__shfl(pa.y, j + 0, 16));
        float wa1 = __int_as_float(__shfl(pa.y, j + 1, 16));
        float wa2 = __int_as_float(__shfl(pa.y, j + 2, 16));
        float wa3 = __int_as_float(__shfl(pa.y, j + 3, 16));
        float wb0 = __int_as_float(__shfl(pb.y, j + 0, 16));
        float wb1 = __int_as_float(__shfl(pb.y, j + 1, 16));
        float wb2 = __int_as_float(__shfl(pb.y, j + 2, 16));
        float wb3 = __int_as_float(__shfl(pb.y, j + 3, 16));
        short8 va0 = *(const short8*)(xb + (size_t)a0 * HDIM + sl * 8);
        short8 vb0 = *(const short8*)(xb + (size_t)b0 * HDIM + sl * 8);
        short8 va1 = *(const short8*)(xb + (size_t)a1 * HDIM + sl * 8);
        short8 vb1 = *(const short8*)(xb + (size_t)b1 * HDIM + sl * 8);
        short8 va2 = *(const short8*)(xb + (size_t)a2 * HDIM + sl * 8);
        short8 vb2 = *(const short8*)(xb + (size_t)b2 * HDIM + sl * 8);
        short8 va3 = *(const short8*)(xb + (size_t)a3 * HDIM + sl * 8);
        short8 vb3 = *(const short8*)(xb + (size_t)b3 * HDIM + sl * 8);
#pragma unroll
        for (int c = 0; c < 8; c++) {
            acc[c] += wa0 * bf2f((ushort_t)va0[c]);
            acc[c] += wa1 * bf2f((ushort_t)va1[c]);
            acc[c] += wa2 * bf2f((ushort_t)va2[c]);
            acc[c] += wa3 * bf2f((ushort_t)va3[c]);
            acc[c] += wb0 * bf2f((ushort_t)vb0[c]);
            acc[c] += wb1 * bf2f((ushort_t)vb1[c]);
            acc[c] += wb2 * bf2f((ushort_t)vb2[c]);
            acc[c] += wb3 * bf2f((ushort_t)vb3[c]);
        }
    }
}

// interleaved pair: both rows' slot-batches issue together (16 loads/iter)
__device__ __forceinline__ void spmm_pair(int2 pa0, int2 pb0, int2 pa1, int2 pb1,
                                          const ushort_t* __restrict__ xb, int sl,
                                          float* __restrict__ accA,
                                          float* __restrict__ accB) {
#pragma unroll
    for (int j = 0; j < 16; j += 4) {
        int   xa0 = __shfl(pa0.x, j + 0, 16), ya0 = __shfl(pb0.x, j + 0, 16);
        int   xa1 = __shfl(pa0.x, j + 1, 16), ya1 = __shfl(pb0.x, j + 1, 16);
        int   xa2 = __shfl(pa0.x, j + 2, 16), ya2 = __shfl(pb0.x, j + 2, 16);
        int   xa3 = __shfl(pa0.x, j + 3, 16), ya3 = __shfl(pb0.x, j + 3, 16);
        int   xb0i = __shfl(pa1.x, j + 0, 16), yb0 = __shfl(pb1.x, j + 0, 16);
        int   xb1i = __shfl(pa1.x, j + 1, 16), yb1 = __shfl(pb1.x, j + 1, 16);
        int   xb2i = __shfl(pa1.x, j + 2, 16), yb2 = __shfl(pb1.x, j + 2, 16);
        int   xb3i = __shfl(pa1.x, j + 3, 16), yb3 = __shfl(pb1.x, j + 3, 16);
        // 16 independent gathers
        short8 u0 = *(const short8*)(xb + (size_t)xa0 * HDIM + sl * 8);
        short8 u1 = *(const short8*)(xb + (size_t)xa1 * HDIM + sl * 8);
        short8 u2 = *(const short8*)(xb + (size_t)xa2 * HDIM + sl * 8);
        short8 u3 = *(const short8*)(xb + (size_t)xa3 * HDIM + sl * 8);
        short8 u4 = *(const short8*)(xb + (size_t)ya0 * HDIM + sl * 8);
        short8 u5 = *(const short8*)(xb + (size_t)ya1 * HDIM + sl * 8);
        short8 u6 = *(const short8*)(xb + (size_t)ya2 * HDIM + sl * 8);
        short8 u7 = *(const short8*)(xb + (size_t)ya3 * HDIM + sl * 8);
        short8 w0 = *(const short8*)(xb + (size_t)xb0i * HDIM + sl * 8);
        short8 w1 = *(const short8*)(xb + (size_t)xb1i * HDIM + sl * 8);
        short8 w2 = *(const short8*)(xb + (size_t)xb2i * HDIM + sl * 8);
        short8 w3 = *(const short8*)(xb + (size_t)xb3i * HDIM + sl * 8);
        short8 w4 = *(const short8*)(xb + (size_t)yb0 * HDIM + sl * 8);
        short8 w5 = *(const short8*)(xb + (size_t)yb1 * HDIM + sl * 8);
        short8 w6 = *(const short8*)(xb + (size_t)yb2 * HDIM + sl * 8);
        short8 w7 = *(const short8*)(xb + (size_t)yb3 * HDIM + sl * 8);
        float fa0 = __int_as_float(__shfl(pa0.y, j + 0, 16));
        float fa1 = __int_as_float(__shfl(pa0.y, j + 1, 16));
        float fa2 = __int_as_float(__shfl(pa0.y, j + 2, 16));
        float fa3 = __int_as_float(__shfl(pa0.y, j + 3, 16));
        float fa4 = __int_as_float(__shfl(pb0.y, j + 0, 16));
        float fa5 = __int_as_float(__shfl(pb0.y, j + 1, 16));
        float fa6 = __int_as_float(__shfl(pb0.y, j + 2, 16));
        float fa7 = __int_as_float(__shfl(pb0.y, j + 3, 16));
        float fb0 = __int_as_float(__shfl(pa1.y, j + 0, 16));
        float fb1 = __int_as_float(__shfl(pa1.y, j + 1, 16));
        float fb2 = __int_as_float(__shfl(pa1.y, j + 2, 16));
        float fb3 = __int_as_float(__shfl(pa1.y, j + 3, 16));
        float fb4 = __int_as_float(__shfl(pb1.y, j + 0, 16));
        float fb5 = __int_as_float(__shfl(pb1.y, j + 1, 16));
        float fb6 = __int_as_float(__shfl(pb1.y, j + 2, 16));
        float fb7 = __int_as_float(__shfl(pb1.y, j + 3, 16));
#pragma unroll
        for (int c = 0; c < 8; c++) {
            accA[c] += fa0 * bf2f((ushort_t)u0[c]);
            accA[c] += fa1 * bf2f((ushort_t)u1[c]);
            accA[c] += fa2 * bf2f((ushort_t)u2[c]);
            accA[c] += fa3 * bf2f((ushort_t)u3[c]);
            accA[c] += fa4 * bf2f((ushort_t)u4[c]);
            accA[c] += fa5 * bf2f((ushort_t)u5[c]);
            accA[c] += fa6 * bf2f((ushort_t)u6[c]);
            accA[c] += fa7 * bf2f((ushort_t)u7[c]);
            accB[c] += fb0 * bf2f((ushort_t)w0[c]);
            accB[c] += fb1 * bf2f((ushort_t)w1[c]);
            accB[c] += fb2 * bf2f((ushort_t)w2[c]);
            accB[c] += fb3 * bf2f((ushort_t)w3[c]);
            accB[c] += fb4 * bf2f((ushort_t)w4[c]);
            accB[c] += fb5 * bf2f((ushort_t)w5[c]);
            accB[c] += fb6 * bf2f((ushort_t)w6[c]);
            accB[c] += fb7 * bf2f((ushort_t)w7[c]);
        }
    }
}

__global__ __launch_bounds__(256)
void layer_fused(const int* __restrict__ row_start, const int2* __restrict__ perm,
                 const ushort_t* __restrict__ xb, const ushort_t* __restrict__ h0b,
                 const ushort_t* __restrict__ Wt, ushort_t* __restrict__ X,
                 float beta) {
    __shared__ short sS[64][SROW];   // 17.4 KB; wave-private 16-row slices
    int t = threadIdx.x;
    int wave = t >> 6, lane = t & 63;
    int grp = lane >> 4, sl = lane & 15;
    int quad = lane >> 4, l16 = lane & 15;   // gemm aliases
    int row0 = blockIdx.x * 64;
    int G = wave * 4 + grp;                  // block-local group 0..15
    int Rg = row0 + G * 4;                   // 4 rows per group

    // row bounds for this group's 4 rows: one lane-parallel load + shfl
    int rbv = 0;
    if (sl <= 4) {
        int idx = Rg + sl; if (idx > N_NODES) idx = N_NODES;
        rbv = row_start[idx];
    }
    int e0[4], e1[4];
#pragma unroll
    for (int r = 0; r < 4; r++) {
        e0[r] = __shfl(rbv, r, 16);
        e1[r] = __shfl(rbv, r + 1, 16);
    }

    // prefetch pair-0 perm entries (rows 0,1)
    int2 cA0 = make_int2(0, 0), cB0 = make_int2(0, 0);
    int2 cA1 = make_int2(0, 0), cB1 = make_int2(0, 0);
    if (e0[0] + sl < e1[0])      cA0 = perm[e0[0] + sl];
    if (e0[0] + 16 + sl < e1[0]) cB0 = perm[e0[0] + 16 + sl];
    if (e0[1] + sl < e1[1])      cA1 = perm[e0[1] + sl];
    if (e0[1] + 16 + sl < e1[1]) cB1 = perm[e0[1] + 16 + sl];

#pragma unroll
    for (int p = 0; p < 2; p++) {
        int ra = 2 * p, rb = 2 * p + 1;
        int rowa = Rg + ra, rowb = Rg + rb;

        // h0 loads early (consumed only at blend)
        short8 ha, hb;
#pragma unroll
        for (int c = 0; c < 8; c++) { ha[c] = 0; hb[c] = 0; }
        if (rowa < N_NODES) ha = *(const short8*)(h0b + (size_t)rowa * HDIM + sl * 8);
        if (rowb < N_NODES) hb = *(const short8*)(h0b + (size_t)rowb * HDIM + sl * 8);

        // prefetch next pair's perm entries
        int2 nA0 = make_int2(0, 0), nB0 = make_int2(0, 0);
        int2 nA1 = make_int2(0, 0), nB1 = make_int2(0, 0);
        if (p == 0) {
            if (e0[2] + sl < e1[2])      nA0 = perm[e0[2] + sl];
            if (e0[2] + 16 + sl < e1[2]) nB0 = perm[e0[2] + 16 + sl];
            if (e0[3] + sl < e1[3])      nA1 = perm[e0[3] + sl];
            if (e0[3] + 16 + sl < e1[3]) nB1 = perm[e0[3] + 16 + sl];
        }

        float accA[8], accB[8];
#pragma unroll
        for (int c = 0; c < 8; c++) { accA[c] = 0.f; accB[c] = 0.f; }

        spmm_pair(cA0, cB0, cA1, cB1, xb, sl, accA, accB);

        // rare tails (degree > 32), per row
        for (int chunk = e0[ra] + 32; chunk < e1[ra]; chunk += 32) {
            int2 qa = make_int2(0, 0), qb = make_int2(0, 0);
            if (chunk + sl < e1[ra])      qa = perm[chunk + sl];
            if (chunk + 16 + sl < e1[ra]) qb = perm[chunk + 16 + sl];
            spmm_proc32(qa, qb, xb, sl, accA);
        }
        for (int chunk = e0[rb] + 32; chunk < e1[rb]; chunk += 32) {
            int2 qa = make_int2(0, 0), qb = make_int2(0, 0);
            if (chunk + sl < e1[rb])      qa = perm[chunk + sl];
            if (chunk + 16 + sl < e1[rb]) qb = perm[chunk + 16 + sl];
            spmm_proc32(qa, qb, xb, sl, accB);
        }

        // blend with h0 and stage to LDS (accs die here)
        short8 oa, ob;
        if (rowa < N_NODES) {
#pragma unroll
            for (int c = 0; c < 8; c++)
                oa[c] = (short)f2bf(0.9f * accA[c] + 0.1f * bf2f((ushort_t)ha[c]));
        } else {
#pragma unroll
            for (int c = 0; c < 8; c++) oa[c] = 0;
        }
        if (rowb < N_NODES) {
#pragma unroll
            for (int c = 0; c < 8; c++)
                ob[c] = (short)f2bf(0.9f * accB[c] + 0.1f * bf2f((ushort_t)hb[c]));
        } else {
#pragma unroll
            for (int c = 0; c < 8; c++) ob[c] = 0;
        }
        *(short8*)&sS[G * 4 + ra][sl * 8] = oa;
        *(short8*)&sS[G * 4 + rb][sl * 8] = ob;

        cA0 = nA0; cB0 = nB0; cA1 = nA1; cB1 = nB1;
    }
    // NO __syncthreads(): gemm below consumes only this wave's own sS rows.

    // ---- gemm phase ----
    short8 afrag[4];
#pragma unroll
    for (int ks = 0; ks < 4; ks++)
        afrag[ks] = *(const short8*)&sS[wave * 16 + l16][ks * 32 + quad * 8];

    floatx4 gacc[8];
#pragma unroll
    for (int nt = 0; nt < 8; nt++) {
        const ushort_t* bp = Wt + (size_t)(nt * 16 + l16) * HDIM + quad * 8;
        floatx4 c = (floatx4){0.f, 0.f, 0.f, 0.f};
#pragma unroll
        for (int ks = 0; ks < 4; ks++) {
            short8 b = *(const short8*)(bp + ks * 32);
            c = __builtin_amdgcn_mfma_f32_16x16x32_bf16(afrag[ks], b, c, 0, 0, 0);
        }
        gacc[nt] = c;
    }
    float g = 1.f - beta;
#pragma unroll
    for (int nt = 0; nt < 8; nt++) {
        int col = nt * 16 + l16;
#pragma unroll
        for (int r = 0; r < 4; r++) {
            int lrow = wave * 16 + quad * 4 + r;
            float s = bf2f((ushort_t)sS[lrow][col]);
            float v = beta * gacc[nt][r] + g * s;
            v = v > 0.f ? v : 0.f;
            X[(size_t)(row0 + lrow) * HDIM + col] = f2bf(v);
        }
    }
}

// ---------------- fc1: out = x @ W1 + b1 (fp32 out), N padded 40->48 ----------------

__global__ void fc1_mfma(const ushort_t* __restrict__ X, const ushort_t* __restrict__ Wt1,
                         const float* __restrict__ b1, float* __restrict__ out) {
    int wave = threadIdx.x >> 6;
    int lane = threadIdx.x & 63;
    int quad = lane >> 4, l16 = lane & 15;
    int row0 = blockIdx.x * 64 + wave * 16;

    int arow = row0 + l16; if (arow > N_NODES - 1) arow = N_NODES - 1;
    const ushort_t* ap = X + (size_t)arow * HDIM + quad * 8;
    short8 afrag[4];
#pragma unroll
    for (int ks = 0; ks < 4; ks++) afrag[ks] = *(const short8*)(ap + ks * 32);

    floatx4 acc[3];
#pragma unroll
    for (int nt = 0; nt < 3; nt++) {
        const ushort_t* bp = Wt1 + (size_t)(nt * 16 + l16) * HDIM + quad * 8;
        floatx4 c = (floatx4){0.f, 0.f, 0.f, 0.f};
#pragma unroll
        for (int ks = 0; ks < 4; ks++) {
            short8 b = *(const short8*)(bp + ks * 32);
            c = __builtin_amdgcn_mfma_f32_16x16x32_bf16(afrag[ks], b, c, 0, 0, 0);
        }
        acc[nt] = c;
    }
#pragma unroll
    for (int nt = 0; nt < 3; nt++) {
        int col = nt * 16 + l16;
        if (col < CDIM) {
            float bias = b1[col];
#pragma unroll
            for (int r = 0; r < 4; r++) {
                int row = row0 + quad * 4 + r;
                if (row < N_NODES)
                    out[(size_t)row * CDIM + col] = acc[nt][r] + bias;
            }
        }
    }
}

// ---------------- launch ----------------

extern "C" void kernel_launch(void* const* d_in, const int* in_sizes, int n_in,
                              void* d_out, int out_size, void* d_ws, size_t ws_size,
                              hipStream_t stream) {
    const float* F     = (const float*)d_in[0];
    const int*   ei    = (const int*)d_in[1];
    const float* normA = (const float*)d_in[2];
    const float* W0    = (const float*)d_in[3];
    const float* b0    = (const float*)d_in[4];
    const float* convW = (const float*)d_in[5];
    const float* W1    = (const float*)d_in[6];
    const float* b1    = (const float*)d_in[7];
    float*       out   = (float*)d_out;

    // workspace layout (bf16 trunk), 16B-aligned
    ushort_t* h0b  = (ushort_t*)d_ws;                     // M_PAD*128
    ushort_t* xab  = h0b + (size_t)M_PAD * HDIM;
    ushort_t* xbb  = xab + (size_t)M_PAD * HDIM;
    ushort_t* Wt0  = xbb + (size_t)M_PAD * HDIM;          // 128*512
    ushort_t* WtL  = Wt0 + 128 * 512;                     // 8*128*128
    ushort_t* Wt1  = WtL + 8 * 128 * 128;                 // 48*128
    int*   row_start = (int*)(Wt1 + 48 * 128);
    int*   cursor    = row_start + (N_NODES + 8);
    int*   cnt       = cursor + (N_NODES + 8);
    int*   bsum      = cnt + (N_NODES + 8);
    int*   boff      = bsum + 256;
    int2*  perm      = (int2*)(boff + 256);               // 8B-aligned

    // CSR build
    hipMemsetAsync(cnt, 0, N_NODES * sizeof(int), stream);
    hist_kernel<<<(E_EDGES + 255) / 256, 256, 0, stream>>>(ei + E_EDGES, cnt);
    scanA<<<NB, 256, 0, stream>>>(cnt, bsum);
    scanB<<<1, 256, 0, stream>>>(bsum, boff);
    scanC<<<NB, 256, 0, stream>>>(cnt, boff, row_start, cursor);
    scatter_kernel<<<(E_EDGES + 255) / 256, 256, 0, stream>>>(ei, normA, cursor, perm);
    prep_weights<<<(128 * 512 + 8 * 128 * 128 + 48 * 128 + 255) / 256, 256, 0, stream>>>(
        W0, convW, W1, Wt0, WtL, Wt1);

    fc0_mfma<<<M_PAD / 32, 256, 0, stream>>>(F, Wt0, b0, h0b);

    // after fc0, x == h0: layer 0 reads h0b as both x and h0
    ushort_t* ping = h0b;
    ushort_t* pong = xab;
    for (int i = 0; i < LAYERS; i++) {
        float beta = logf(0.5f / (float)(i + 1) + 1.0f);
        layer_fused<<<M_PAD / 64, 256, 0, stream>>>(
            row_start, perm, ping, h0b, WtL + (size_t)i * HDIM * HDIM, pong, beta);
        if (i == 0) { ping = xab; pong = xbb; }
        else { ushort_t* tmp = ping; ping = pong; pong = tmp; }
    }
    // L0->xab, L1->xbb, ..., L7->xbb; ping == xbb here
    fc1_mfma<<<M_PAD / 64, 256, 0, stream>>>(ping, Wt1, b1, out);
}

// Round 11
// 689.492 us; speedup vs baseline: 1.0855x; 1.0855x over previous
//
#include <hip/hip_runtime.h>
#include <hip/hip_bf16.h>
#include <math.h>

#define N_NODES 50000
#define M_PAD   50048           // 782 * 64 rows; fc0 uses 1564 * 32
#define E_EDGES 800000
#define IN_DIM  512
#define HDIM    128
#define CDIM    40
#define LAYERS  8
#define NB      196             // scan blocks: ceil(50000/256)

typedef __attribute__((ext_vector_type(8))) short short8;
typedef __attribute__((ext_vector_type(4))) float floatx4;
typedef unsigned short ushort_t;

__device__ inline float bf2f(unsigned short u) {
    return __uint_as_float(((unsigned)u) << 16);
}
__device__ inline unsigned short f2bf(float v) {
    __hip_bfloat16 b = __float2bfloat16(v);
    return *reinterpret_cast<unsigned short*>(&b);
}

// ---------------- CSR build ----------------

__global__ void hist_kernel(const int* __restrict__ dst, int* __restrict__ cnt) {
    int i = blockIdx.x * blockDim.x + threadIdx.x;
    if (i < E_EDGES) atomicAdd(&cnt[dst[i]], 1);
}

__global__ void scanA(const int* __restrict__ cnt, int* __restrict__ bsum) {
    __shared__ int sm[256];
    int t = threadIdx.x, i = blockIdx.x * 256 + t;
    sm[t] = (i < N_NODES) ? cnt[i] : 0;
    __syncthreads();
    for (int d = 128; d > 0; d >>= 1) {
        if (t < d) sm[t] += sm[t + d];
        __syncthreads();
    }
    if (t == 0) bsum[blockIdx.x] = sm[0];
}

__global__ void scanB(const int* __restrict__ bsum, int* __restrict__ boff) {
    __shared__ int sm[256];
    int t = threadIdx.x;
    sm[t] = (t < NB) ? bsum[t] : 0;
    __syncthreads();
    for (int d = 1; d < 256; d <<= 1) {
        int v = (t >= d) ? sm[t - d] : 0;
        __syncthreads();
        sm[t] += v;
        __syncthreads();
    }
    if (t < NB) boff[t] = (t > 0) ? sm[t - 1] : 0;
}

__global__ void scanC(const int* __restrict__ cnt, const int* __restrict__ boff,
                      int* __restrict__ row_start, int* __restrict__ cursor) {
    __shared__ int sm[256];
    int t = threadIdx.x, i = blockIdx.x * 256 + t;
    int v = (i < N_NODES) ? cnt[i] : 0;
    sm[t] = v;
    __syncthreads();
    for (int d = 1; d < 256; d <<= 1) {
        int x = (t >= d) ? sm[t - d] : 0;
        __syncthreads();
        sm[t] += x;
        __syncthreads();
    }
    if (i < N_NODES) {
        int incl = boff[blockIdx.x] + sm[t];
        int excl = incl - v;
        row_start[i] = excl;
        cursor[i]    = excl;
        if (i == N_NODES - 1) row_start[N_NODES] = incl;
    }
}

__global__ void scatter_kernel(const int* __restrict__ ei, const float* __restrict__ normA,
                               int* __restrict__ cursor, int2* __restrict__ perm) {
    int i = blockIdx.x * blockDim.x + threadIdx.x;
    if (i >= E_EDGES) return;
    int d = ei[E_EDGES + i];
    int idx = atomicAdd(&cursor[d], 1);
    perm[idx] = make_int2(ei[i], __float_as_int(normA[i]));
}

// ---------------- weight prep: transpose + bf16 convert ----------------

__global__ void prep_weights(const float* __restrict__ W0, const float* __restrict__ convW,
                             const float* __restrict__ W1,
                             ushort_t* __restrict__ Wt0, ushort_t* __restrict__ WtL,
                             ushort_t* __restrict__ Wt1) {
    int i = blockIdx.x * blockDim.x + threadIdx.x;
    if (i < 128 * 512) {
        int n = i >> 9, k = i & 511;
        Wt0[i] = f2bf(W0[k * HDIM + n]);
        return;
    }
    int j = i - 128 * 512;
    if (j < 8 * 128 * 128) {
        int l = j >> 14, rem = j & 16383, n = rem >> 7, k = rem & 127;
        WtL[j] = f2bf(convW[l * 16384 + k * HDIM + n]);
        return;
    }
    int m = j - 8 * 128 * 128;
    if (m < 48 * 128) {
        int n = m >> 7, k = m & 127;
        Wt1[m] = (n < CDIM) ? f2bf(W1[k * CDIM + n]) : (ushort_t)0;
    }
}

// ---------------- fc0: x = relu(F @ W0 + b0) -> h0b (bf16) ----------------
// Round-9 structure kept: triple-buffer gll staging, counted vmcnt + s_barrier.

__global__ __launch_bounds__(256)
void fc0_mfma(const float* __restrict__ F, const ushort_t* __restrict__ Wt0,
              const float* __restrict__ b0, ushort_t* __restrict__ h0b) {
    __shared__ float sA[3][32 * 128];   // 3 x 16KB
    int t = threadIdx.x;
    int wave = t >> 6, lane = t & 63;
    int quad = lane >> 4, l16 = lane & 15;
    int R0 = blockIdx.x * 32;

    const ushort_t* bbase = Wt0 + (size_t)(wave * 32 + l16) * IN_DIM + quad * 8;

    floatx4 acc[2][2];   // [rowfrag][nt]
#pragma unroll
    for (int rf = 0; rf < 2; rf++)
#pragma unroll
        for (int nt = 0; nt < 2; nt++) acc[rf][nt] = (floatx4){0.f, 0.f, 0.f, 0.f};

    auto stage = [&](int cc, int buf) {
#pragma unroll
        for (int i = 0; i < 4; i++) {
            int X = i * 4096 + wave * 1024 + lane * 16;     // byte in 16KB chunk
            int row = X >> 9;
            int colb = (X & 511) ^ ((row & 7) << 4);
            int gr = R0 + row; if (gr > N_NODES - 1) gr = N_NODES - 1;
            const float* src = F + (size_t)gr * IN_DIM + cc * 128 + (colb >> 2);
            __builtin_amdgcn_global_load_lds(
                (const __attribute__((address_space(1))) unsigned int*)src,
                (__attribute__((address_space(3))) unsigned int*)&sA[buf][i * 1024 + wave * 256],
                16, 0, 0);
        }
    };

    stage(0, 0);
    stage(1, 1);

    int mask = (l16 & 7) << 4;                 // per-lane read swizzle (bytes)
    int ib0 = ((quad << 5) ^ mask) >> 2;       // float offsets within ks-block
    int ib1 = (((quad << 5) | 16) ^ mask) >> 2;

#pragma unroll
    for (int cc = 0; cc < 4; cc++) {
        asm volatile("s_waitcnt vmcnt(4)" ::: "memory");   // chunk cc landed (in-order)
        __builtin_amdgcn_s_barrier();
        __builtin_amdgcn_sched_barrier(0);
        if (cc < 2) stage(cc + 2, (cc + 2) % 3);
        const float* bufp = &sA[cc % 3][0];
        const float* r0p = bufp + l16 * 128;
        const float* r1p = bufp + (l16 + 16) * 128;
#pragma unroll
        for (int k2 = 0; k2 < 4; k2++) {
            int ks = cc * 4 + k2;
            float4 f00 = *(const float4*)(r0p + k2 * 32 + ib0);
            float4 f01 = *(const float4*)(r0p + k2 * 32 + ib1);
            float4 f10 = *(const float4*)(r1p + k2 * 32 + ib0);
            float4 f11 = *(const float4*)(r1p + k2 * 32 + ib1);
            short8 a0, a1;
            a0[0] = (short)f2bf(f00.x); a0[1] = (short)f2bf(f00.y);
            a0[2] = (short)f2bf(f00.z); a0[3] = (short)f2bf(f00.w);
            a0[4] = (short)f2bf(f01.x); a0[5] = (short)f2bf(f01.y);
            a0[6] = (short)f2bf(f01.z); a0[7] = (short)f2bf(f01.w);
            a1[0] = (short)f2bf(f10.x); a1[1] = (short)f2bf(f10.y);
            a1[2] = (short)f2bf(f10.z); a1[3] = (short)f2bf(f10.w);
            a1[4] = (short)f2bf(f11.x); a1[5] = (short)f2bf(f11.y);
            a1[6] = (short)f2bf(f11.z); a1[7] = (short)f2bf(f11.w);
#pragma unroll
            for (int nt = 0; nt < 2; nt++) {
                short8 b = *(const short8*)(bbase + (size_t)nt * 16 * IN_DIM + ks * 32);
                acc[0][nt] = __builtin_amdgcn_mfma_f32_16x16x32_bf16(a0, b, acc[0][nt], 0, 0, 0);
                acc[1][nt] = __builtin_amdgcn_mfma_f32_16x16x32_bf16(a1, b, acc[1][nt], 0, 0, 0);
            }
        }
    }

#pragma unroll
    for (int nt = 0; nt < 2; nt++) {
        int col = wave * 32 + nt * 16 + l16;
        float bias = b0[col];
#pragma unroll
        for (int r = 0; r < 4; r++) {
            int row = R0 + quad * 4 + r;
            float v = acc[0][nt][r] + bias;
            v = v > 0.f ? v : 0.f;
            h0b[(size_t)row * HDIM + col] = f2bf(v);
        }
#pragma unroll
        for (int r = 0; r < 4; r++) {
            int row = R0 + 16 + quad * 4 + r;
            float v = acc[1][nt][r] + bias;
            v = v > 0.f ? v : 0.f;
            h0b[(size_t)row * HDIM + col] = f2bf(v);
        }
    }
}

// -------- fused layer: sup = 0.9*(A x)+0.1*h0 (into LDS); x' = relu(beta*(sup W)+(1-beta)*sup)
// block = 64 rows, 256 thr / 4 waves; 16-lane group owns 4 rows SERIALLY
// (round-8 structure, best measured). Round-11: __launch_bounds__(256,4)
// caps VGPR at 128 -> 4 waves/SIMD resident (round-10 counters: VGPR=184
// gave 2 waves/SIMD, 8% occupancy, VALUBusy 18.8% -- wave-starved, not
// BW/VALU-bound). Per-wave ILP attempts all traded registers for waves at
// a net loss; this trades back.

#define SROW 136   // 128 + 8 pad

__device__ __forceinline__ void spmm_proc32(int2 pa, int2 pb,
                                            const ushort_t* __restrict__ xb,
                                            int sl, float* __restrict__ acc) {
#pragma unroll
    for (int j = 0; j < 16; j += 4) {
        int   a0 = __shfl(pa.x, j + 0, 16), b0 = __shfl(pb.x, j + 0, 16);
        int   a1 = __shfl(pa.x, j + 1, 16), b1 = __shfl(pb.x, j + 1, 16);
        int   a2 = __shfl(pa.x, j + 2, 16), b2 = __shfl(pb.x, j + 2, 16);
        int   a3 = __shfl(pa.x, j + 3, 16), b3 = __shfl(pb.x, j + 3, 16);
        float wa0 = __int_as_float(__shfl(pa.y, j + 0, 16));
        float wa1 = __int_as_float(__shfl(pa.y, j + 1, 16));
        float wa2 = __int_as_float(__shfl(pa.y, j + 2, 16));
        float wa3 = __int_as_float(__shfl(pa.y, j + 3, 16));
        float wb0 = __int_as_float(__shfl(pb.y, j + 0, 16));
        float wb1 = __int_as_float(__shfl(pb.y, j + 1, 16));
        float wb2 = __int_as_float(__shfl(pb.y, j + 2, 16));
        float wb3 = __int_as_float(__shfl(pb.y, j + 3, 16));
        short8 va0 = *(const short8*)(xb + (size_t)a0 * HDIM + sl * 8);
        short8 vb0 = *(const short8*)(xb + (size_t)b0 * HDIM + sl * 8);
        short8 va1 = *(const short8*)(xb + (size_t)a1 * HDIM + sl * 8);
        short8 vb1 = *(const short8*)(xb + (size_t)b1 * HDIM + sl * 8);
        short8 va2 = *(const short8*)(xb + (size_t)a2 * HDIM + sl * 8);
        short8 vb2 = *(const short8*)(xb + (size_t)b2 * HDIM + sl * 8);
        short8 va3 = *(const short8*)(xb + (size_t)a3 * HDIM + sl * 8);
        short8 vb3 = *(const short8*)(xb + (size_t)b3 * HDIM + sl * 8);
#pragma unroll
        for (int c = 0; c < 8; c++) {
            acc[c] += wa0 * bf2f((ushort_t)va0[c]);
            acc[c] += wa1 * bf2f((ushort_t)va1[c]);
            acc[c] += wa2 * bf2f((ushort_t)va2[c]);
            acc[c] += wa3 * bf2f((ushort_t)va3[c]);
            acc[c] += wb0 * bf2f((ushort_t)vb0[c]);
            acc[c] += wb1 * bf2f((ushort_t)vb1[c]);
            acc[c] += wb2 * bf2f((ushort_t)vb2[c]);
            acc[c] += wb3 * bf2f((ushort_t)vb3[c]);
        }
    }
}

__global__ __launch_bounds__(256, 4)
void layer_fused(const int* __restrict__ row_start, const int2* __restrict__ perm,
                 const ushort_t* __restrict__ xb, const ushort_t* __restrict__ h0b,
                 const ushort_t* __restrict__ Wt, ushort_t* __restrict__ X,
                 float beta) {
    __shared__ short sS[64][SROW];   // 17.4 KB; wave-private 16-row slices
    int t = threadIdx.x;
    int wave = t >> 6, lane = t & 63;
    int grp = lane >> 4, sl = lane & 15;
    int quad = lane >> 4, l16 = lane & 15;   // gemm aliases
    int row0 = blockIdx.x * 64;
    int G = wave * 4 + grp;                  // block-local group 0..15
    int Rg = row0 + G * 4;                   // 4 rows per group

    // row bounds for this group's 4 rows: one lane-parallel load + shfl
    int rbv = 0;
    if (sl <= 4) {
        int idx = Rg + sl; if (idx > N_NODES) idx = N_NODES;
        rbv = row_start[idx];
    }
    int e0[4], e1[4];
#pragma unroll
    for (int r = 0; r < 4; r++) {
        e0[r] = __shfl(rbv, r, 16);
        e1[r] = __shfl(rbv, r + 1, 16);
    }

    // prefetch row 0's chunk-0 perm entries
    int2 pA = make_int2(0, 0), pB = make_int2(0, 0);
    if (e0[0] + sl < e1[0])      pA = perm[e0[0] + sl];
    if (e0[0] + 16 + sl < e1[0]) pB = perm[e0[0] + 16 + sl];

#pragma unroll
    for (int r = 0; r < 4; r++) {
        int row = Rg + r;

        // issue h0 load early (consumed only at blend)
        short8 h;
#pragma unroll
        for (int c = 0; c < 8; c++) h[c] = 0;
        if (row < N_NODES) h = *(const short8*)(h0b + (size_t)row * HDIM + sl * 8);

        // prefetch next row's perm before touching this row's gathers
        int2 nA = make_int2(0, 0), nB = make_int2(0, 0);
        if (r < 3) {
            if (e0[r + 1] + sl < e1[r + 1])      nA = perm[e0[r + 1] + sl];
            if (e0[r + 1] + 16 + sl < e1[r + 1]) nB = perm[e0[r + 1] + 16 + sl];
        }

        float acc[8];
#pragma unroll
        for (int c = 0; c < 8; c++) acc[c] = 0.f;

        spmm_proc32(pA, pB, xb, sl, acc);

        // rare tails (degree > 32)
        for (int chunk = e0[r] + 32; chunk < e1[r]; chunk += 32) {
            int2 qa = make_int2(0, 0), qb = make_int2(0, 0);
            if (chunk + sl < e1[r])      qa = perm[chunk + sl];
            if (chunk + 16 + sl < e1[r]) qb = perm[chunk + 16 + sl];
            spmm_proc32(qa, qb, xb, sl, acc);
        }

        // blend with h0 and stage to LDS (acc dies here)
        short8 o;
        if (row < N_NODES) {
#pragma unroll
            for (int c = 0; c < 8; c++)
                o[c] = (short)f2bf(0.9f * acc[c] + 0.1f * bf2f((ushort_t)h[c]));
        } else {
#pragma unroll
            for (int c = 0; c < 8; c++) o[c] = 0;
        }
        *(short8*)&sS[G * 4 + r][sl * 8] = o;

        pA = nA; pB = nB;
    }
    // NO __syncthreads(): gemm below consumes only this wave's own sS rows.

    // ---- gemm phase ----
    short8 afrag[4];
#pragma unroll
    for (int ks = 0; ks < 4; ks++)
        afrag[ks] = *(const short8*)&sS[wave * 16 + l16][ks * 32 + quad * 8];

    floatx4 gacc[8];
#pragma unroll
    for (int nt = 0; nt < 8; nt++) {
        const ushort_t* bp = Wt + (size_t)(nt * 16 + l16) * HDIM + quad * 8;
        floatx4 c = (floatx4){0.f, 0.f, 0.f, 0.f};
#pragma unroll
        for (int ks = 0; ks < 4; ks++) {
            short8 b = *(const short8*)(bp + ks * 32);
            c = __builtin_amdgcn_mfma_f32_16x16x32_bf16(afrag[ks], b, c, 0, 0, 0);
        }
        gacc[nt] = c;
    }
    float g = 1.f - beta;
#pragma unroll
    for (int nt = 0; nt < 8; nt++) {
        int col = nt * 16 + l16;
#pragma unroll
        for (int r = 0; r < 4; r++) {
            int lrow = wave * 16 + quad * 4 + r;
            float s = bf2f((ushort_t)sS[lrow][col]);
            float v = beta * gacc[nt][r] + g * s;
            v = v > 0.f ? v : 0.f;
            X[(size_t)(row0 + lrow) * HDIM + col] = f2bf(v);
        }
    }
}

// ---------------- fc1: out = x @ W1 + b1 (fp32 out), N padded 40->48 ----------------

__global__ void fc1_mfma(const ushort_t* __restrict__ X, const ushort_t* __restrict__ Wt1,
                         const float* __restrict__ b1, float* __restrict__ out) {
    int wave = threadIdx.x >> 6;
    int lane = threadIdx.x & 63;
    int quad = lane >> 4, l16 = lane & 15;
    int row0 = blockIdx.x * 64 + wave * 16;

    int arow = row0 + l16; if (arow > N_NODES - 1) arow = N_NODES - 1;
    const ushort_t* ap = X + (size_t)arow * HDIM + quad * 8;
    short8 afrag[4];
#pragma unroll
    for (int ks = 0; ks < 4; ks++) afrag[ks] = *(const short8*)(ap + ks * 32);

    floatx4 acc[3];
#pragma unroll
    for (int nt = 0; nt < 3; nt++) {
        const ushort_t* bp = Wt1 + (size_t)(nt * 16 + l16) * HDIM + quad * 8;
        floatx4 c = (floatx4){0.f, 0.f, 0.f, 0.f};
#pragma unroll
        for (int ks = 0; ks < 4; ks++) {
            short8 b = *(const short8*)(bp + ks * 32);
            c = __builtin_amdgcn_mfma_f32_16x16x32_bf16(afrag[ks], b, c, 0, 0, 0);
        }
        acc[nt] = c;
    }
#pragma unroll
    for (int nt = 0; nt < 3; nt++) {
        int col = nt * 16 + l16;
        if (col < CDIM) {
            float bias = b1[col];
#pragma unroll
            for (int r = 0; r < 4; r++) {
                int row = row0 + quad * 4 + r;
                if (row < N_NODES)
                    out[(size_t)row * CDIM + col] = acc[nt][r] + bias;
            }
        }
    }
}

// ---------------- launch ----------------

extern "C" void kernel_launch(void* const* d_in, const int* in_sizes, int n_in,
                              void* d_out, int out_size, void* d_ws, size_t ws_size,
                              hipStream_t stream) {
    const float* F     = (const float*)d_in[0];
    const int*   ei    = (const int*)d_in[1];
    const float* normA = (const float*)d_in[2];
    const float* W0    = (const float*)d_in[3];
    const float* b0    = (const float*)d_in[4];
    const float* convW = (const float*)d_in[5];
    const float* W1    = (const float*)d_in[6];
    const float* b1    = (const float*)d_in[7];
    float*       out   = (float*)d_out;

    // workspace layout (bf16 trunk), 16B-aligned
    ushort_t* h0b  = (ushort_t*)d_ws;                     // M_PAD*128
    ushort_t* xab  = h0b + (size_t)M_PAD * HDIM;
    ushort_t* xbb  = xab + (size_t)M_PAD * HDIM;
    ushort_t* Wt0  = xbb + (size_t)M_PAD * HDIM;          // 128*512
    ushort_t* WtL  = Wt0 + 128 * 512;                     // 8*128*128
    ushort_t* Wt1  = WtL + 8 * 128 * 128;                 // 48*128
    int*   row_start = (int*)(Wt1 + 48 * 128);
    int*   cursor    = row_start + (N_NODES + 8);
    int*   cnt       = cursor + (N_NODES + 8);
    int*   bsum      = cnt + (N_NODES + 8);
    int*   boff      = bsum + 256;
    int2*  perm      = (int2*)(boff + 256);               // 8B-aligned

    // CSR build
    hipMemsetAsync(cnt, 0, N_NODES * sizeof(int), stream);
    hist_kernel<<<(E_EDGES + 255) / 256, 256, 0, stream>>>(ei + E_EDGES, cnt);
    scanA<<<NB, 256, 0, stream>>>(cnt, bsum);
    scanB<<<1, 256, 0, stream>>>(bsum, boff);
    scanC<<<NB, 256, 0, stream>>>(cnt, boff, row_start, cursor);
    scatter_kernel<<<(E_EDGES + 255) / 256, 256, 0, stream>>>(ei, normA, cursor, perm);
    prep_weights<<<(128 * 512 + 8 * 128 * 128 + 48 * 128 + 255) / 256, 256, 0, stream>>>(
        W0, convW, W1, Wt0, WtL, Wt1);

    fc0_mfma<<<M_PAD / 32, 256, 0, stream>>>(F, Wt0, b0, h0b);

    // after fc0, x == h0: layer 0 reads h0b as both x and h0
    ushort_t* ping = h0b;
    ushort_t* pong = xab;
    for (int i = 0; i < LAYERS; i++) {
        float beta = logf(0.5f / (float)(i + 1) + 1.0f);
        layer_fused<<<M_PAD / 64, 256, 0, stream>>>(
            row_start, perm, ping, h0b, WtL + (size_t)i * HDIM * HDIM, pong, beta);
        if (i == 0) { ping = xab; pong = xbb; }
        else { ushort_t* tmp = ping; ping = pong; pong = tmp; }
    }
    // L0->xab, L1->xbb, ..., L7->xbb; ping == xbb here
    fc1_mfma<<<M_PAD / 64, 256, 0, stream>>>(ping, Wt1, b1, out);
}

// Round 12
// 677.441 us; speedup vs baseline: 1.1048x; 1.0178x over previous
//
#include <hip/hip_runtime.h>
#include <hip/hip_bf16.h>
#include <math.h>

#define N_NODES 50000
#define M_PAD   50048           // 782 * 64 rows; fc0 uses 1564 * 32
#define E_EDGES 800000
#define IN_DIM  512
#define HDIM    128
#define CDIM    40
#define LAYERS  8
#define NB      196             // scan blocks: ceil(50000/256)

typedef __attribute__((ext_vector_type(8))) short short8;
typedef __attribute__((ext_vector_type(4))) float floatx4;
typedef unsigned short ushort_t;

__device__ inline float bf2f(unsigned short u) {
    return __uint_as_float(((unsigned)u) << 16);
}
__device__ inline unsigned short f2bf(float v) {
    __hip_bfloat16 b = __float2bfloat16(v);
    return *reinterpret_cast<unsigned short*>(&b);
}

// ---------------- CSR build ----------------

__global__ void hist_kernel(const int* __restrict__ dst, int* __restrict__ cnt) {
    int i = blockIdx.x * blockDim.x + threadIdx.x;
    if (i < E_EDGES) atomicAdd(&cnt[dst[i]], 1);
}

__global__ void scanA(const int* __restrict__ cnt, int* __restrict__ bsum) {
    __shared__ int sm[256];
    int t = threadIdx.x, i = blockIdx.x * 256 + t;
    sm[t] = (i < N_NODES) ? cnt[i] : 0;
    __syncthreads();
    for (int d = 128; d > 0; d >>= 1) {
        if (t < d) sm[t] += sm[t + d];
        __syncthreads();
    }
    if (t == 0) bsum[blockIdx.x] = sm[0];
}

__global__ void scanB(const int* __restrict__ bsum, int* __restrict__ boff) {
    __shared__ int sm[256];
    int t = threadIdx.x;
    sm[t] = (t < NB) ? bsum[t] : 0;
    __syncthreads();
    for (int d = 1; d < 256; d <<= 1) {
        int v = (t >= d) ? sm[t - d] : 0;
        __syncthreads();
        sm[t] += v;
        __syncthreads();
    }
    if (t < NB) boff[t] = (t > 0) ? sm[t - 1] : 0;
}

__global__ void scanC(const int* __restrict__ cnt, const int* __restrict__ boff,
                      int* __restrict__ row_start, int* __restrict__ cursor) {
    __shared__ int sm[256];
    int t = threadIdx.x, i = blockIdx.x * 256 + t;
    int v = (i < N_NODES) ? cnt[i] : 0;
    sm[t] = v;
    __syncthreads();
    for (int d = 1; d < 256; d <<= 1) {
        int x = (t >= d) ? sm[t - d] : 0;
        __syncthreads();
        sm[t] += x;
        __syncthreads();
    }
    if (i < N_NODES) {
        int incl = boff[blockIdx.x] + sm[t];
        int excl = incl - v;
        row_start[i] = excl;
        cursor[i]    = excl;
        if (i == N_NODES - 1) row_start[N_NODES] = incl;
    }
}

__global__ void scatter_kernel(const int* __restrict__ ei, const float* __restrict__ normA,
                               int* __restrict__ cursor, int2* __restrict__ perm) {
    int i = blockIdx.x * blockDim.x + threadIdx.x;
    if (i >= E_EDGES) return;
    int d = ei[E_EDGES + i];
    int idx = atomicAdd(&cursor[d], 1);
    perm[idx] = make_int2(ei[i], __float_as_int(normA[i]));
}

// ---------------- weight prep: transpose + bf16 convert ----------------

__global__ void prep_weights(const float* __restrict__ W0, const float* __restrict__ convW,
                             const float* __restrict__ W1,
                             ushort_t* __restrict__ Wt0, ushort_t* __restrict__ WtL,
                             ushort_t* __restrict__ Wt1) {
    int i = blockIdx.x * blockDim.x + threadIdx.x;
    if (i < 128 * 512) {
        int n = i >> 9, k = i & 511;
        Wt0[i] = f2bf(W0[k * HDIM + n]);
        return;
    }
    int j = i - 128 * 512;
    if (j < 8 * 128 * 128) {
        int l = j >> 14, rem = j & 16383, n = rem >> 7, k = rem & 127;
        WtL[j] = f2bf(convW[l * 16384 + k * HDIM + n]);
        return;
    }
    int m = j - 8 * 128 * 128;
    if (m < 48 * 128) {
        int n = m >> 7, k = m & 127;
        Wt1[m] = (n < CDIM) ? f2bf(W1[k * CDIM + n]) : (ushort_t)0;
    }
}

// ---------------- fc0: x = relu(F @ W0 + b0) -> h0b (bf16) ----------------
// Round-9 structure: triple-buffer gll staging, counted vmcnt + s_barrier.

__global__ __launch_bounds__(256)
void fc0_mfma(const float* __restrict__ F, const ushort_t* __restrict__ Wt0,
              const float* __restrict__ b0, ushort_t* __restrict__ h0b) {
    __shared__ float sA[3][32 * 128];   // 3 x 16KB
    int t = threadIdx.x;
    int wave = t >> 6, lane = t & 63;
    int quad = lane >> 4, l16 = lane & 15;
    int R0 = blockIdx.x * 32;

    const ushort_t* bbase = Wt0 + (size_t)(wave * 32 + l16) * IN_DIM + quad * 8;

    floatx4 acc[2][2];   // [rowfrag][nt]
#pragma unroll
    for (int rf = 0; rf < 2; rf++)
#pragma unroll
        for (int nt = 0; nt < 2; nt++) acc[rf][nt] = (floatx4){0.f, 0.f, 0.f, 0.f};

    auto stage = [&](int cc, int buf) {
#pragma unroll
        for (int i = 0; i < 4; i++) {
            int X = i * 4096 + wave * 1024 + lane * 16;     // byte in 16KB chunk
            int row = X >> 9;
            int colb = (X & 511) ^ ((row & 7) << 4);
            int gr = R0 + row; if (gr > N_NODES - 1) gr = N_NODES - 1;
            const float* src = F + (size_t)gr * IN_DIM + cc * 128 + (colb >> 2);
            __builtin_amdgcn_global_load_lds(
                (const __attribute__((address_space(1))) unsigned int*)src,
                (__attribute__((address_space(3))) unsigned int*)&sA[buf][i * 1024 + wave * 256],
                16, 0, 0);
        }
    };

    stage(0, 0);
    stage(1, 1);

    int mask = (l16 & 7) << 4;                 // per-lane read swizzle (bytes)
    int ib0 = ((quad << 5) ^ mask) >> 2;       // float offsets within ks-block
    int ib1 = (((quad << 5) | 16) ^ mask) >> 2;

#pragma unroll
    for (int cc = 0; cc < 4; cc++) {
        asm volatile("s_waitcnt vmcnt(4)" ::: "memory");   // chunk cc landed (in-order)
        __builtin_amdgcn_s_barrier();
        __builtin_amdgcn_sched_barrier(0);
        if (cc < 2) stage(cc + 2, (cc + 2) % 3);
        const float* bufp = &sA[cc % 3][0];
        const float* r0p = bufp + l16 * 128;
        const float* r1p = bufp + (l16 + 16) * 128;
#pragma unroll
        for (int k2 = 0; k2 < 4; k2++) {
            int ks = cc * 4 + k2;
            float4 f00 = *(const float4*)(r0p + k2 * 32 + ib0);
            float4 f01 = *(const float4*)(r0p + k2 * 32 + ib1);
            float4 f10 = *(const float4*)(r1p + k2 * 32 + ib0);
            float4 f11 = *(const float4*)(r1p + k2 * 32 + ib1);
            short8 a0, a1;
            a0[0] = (short)f2bf(f00.x); a0[1] = (short)f2bf(f00.y);
            a0[2] = (short)f2bf(f00.z); a0[3] = (short)f2bf(f00.w);
            a0[4] = (short)f2bf(f01.x); a0[5] = (short)f2bf(f01.y);
            a0[6] = (short)f2bf(f01.z); a0[7] = (short)f2bf(f01.w);
            a1[0] = (short)f2bf(f10.x); a1[1] = (short)f2bf(f10.y);
            a1[2] = (short)f2bf(f10.z); a1[3] = (short)f2bf(f10.w);
            a1[4] = (short)f2bf(f11.x); a1[5] = (short)f2bf(f11.y);
            a1[6] = (short)f2bf(f11.z); a1[7] = (short)f2bf(f11.w);
#pragma unroll
            for (int nt = 0; nt < 2; nt++) {
                short8 b = *(const short8*)(bbase + (size_t)nt * 16 * IN_DIM + ks * 32);
                acc[0][nt] = __builtin_amdgcn_mfma_f32_16x16x32_bf16(a0, b, acc[0][nt], 0, 0, 0);
                acc[1][nt] = __builtin_amdgcn_mfma_f32_16x16x32_bf16(a1, b, acc[1][nt], 0, 0, 0);
            }
        }
    }

#pragma unroll
    for (int nt = 0; nt < 2; nt++) {
        int col = wave * 32 + nt * 16 + l16;
        float bias = b0[col];
#pragma unroll
        for (int r = 0; r < 4; r++) {
            int row = R0 + quad * 4 + r;
            float v = acc[0][nt][r] + bias;
            v = v > 0.f ? v : 0.f;
            h0b[(size_t)row * HDIM + col] = f2bf(v);
        }
#pragma unroll
        for (int r = 0; r < 4; r++) {
            int row = R0 + 16 + quad * 4 + r;
            float v = acc[1][nt][r] + bias;
            v = v > 0.f ? v : 0.f;
            h0b[(size_t)row * HDIM + col] = f2bf(v);
        }
    }
}

// -------- fused layer: sup = 0.9*(A x)+0.1*h0 (into LDS); x' = relu(beta*(sup W)+(1-beta)*sup)
// Round-9 structure restored (best measured, 645.6 total): block = 64 rows,
// 256 thr / 4 waves; 16-lane group owns 4 rows serially; dynamic edge trip
// count; no barrier (wave-private sS slices).
// Round-12 delta: __launch_bounds__(256,3) -- cap 168 VGPR, ABOVE the natural
// ~150-165 allocation (no spill) but below the 170+ drift that drops residency
// to 2 waves/SIMD (round-10's 184-VGPR failure mode). bounds(4)=cap-128
// spilled (round-11 +44us); this is the safe side of the ridge.

#define SROW 136   // 128 + 8 pad

__device__ __forceinline__ void spmm_proc32(int2 pa, int2 pb,
                                            const ushort_t* __restrict__ xb,
                                            int sl, float* __restrict__ acc) {
#pragma unroll
    for (int j = 0; j < 16; j += 4) {
        int   a0 = __shfl(pa.x, j + 0, 16), b0 = __shfl(pb.x, j + 0, 16);
        int   a1 = __shfl(pa.x, j + 1, 16), b1 = __shfl(pb.x, j + 1, 16);
        int   a2 = __shfl(pa.x, j + 2, 16), b2 = __shfl(pb.x, j + 2, 16);
        int   a3 = __shfl(pa.x, j + 3, 16), b3 = __shfl(pb.x, j + 3, 16);
        float wa0 = __int_as_float(__shfl(pa.y, j + 0, 16));
        float wa1 = __int_as_float(__shfl(pa.y, j + 1, 16));
        float wa2 = __int_as_float(__shfl(pa.y, j + 2, 16));
        float wa3 = __int_as_float(__shfl(pa.y, j + 3, 16));
        float wb0 = __int_as_float(__shfl(pb.y, j + 0, 16));
        float wb1 = __int_as_float(__shfl(pb.y, j + 1, 16));
        float wb2 = __int_as_float(__shfl(pb.y, j + 2, 16));
        float wb3 = __int_as_float(__shfl(pb.y, j + 3, 16));
        short8 va0 = *(const short8*)(xb + (size_t)a0 * HDIM + sl * 8);
        short8 vb0 = *(const short8*)(xb + (size_t)b0 * HDIM + sl * 8);
        short8 va1 = *(const short8*)(xb + (size_t)a1 * HDIM + sl * 8);
        short8 vb1 = *(const short8*)(xb + (size_t)b1 * HDIM + sl * 8);
        short8 va2 = *(const short8*)(xb + (size_t)a2 * HDIM + sl * 8);
        short8 vb2 = *(const short8*)(xb + (size_t)b2 * HDIM + sl * 8);
        short8 va3 = *(const short8*)(xb + (size_t)a3 * HDIM + sl * 8);
        short8 vb3 = *(const short8*)(xb + (size_t)b3 * HDIM + sl * 8);
#pragma unroll
        for (int c = 0; c < 8; c++) {
            acc[c] += wa0 * bf2f((ushort_t)va0[c]);
            acc[c] += wa1 * bf2f((ushort_t)va1[c]);
            acc[c] += wa2 * bf2f((ushort_t)va2[c]);
            acc[c] += wa3 * bf2f((ushort_t)va3[c]);
            acc[c] += wb0 * bf2f((ushort_t)vb0[c]);
            acc[c] += wb1 * bf2f((ushort_t)vb1[c]);
            acc[c] += wb2 * bf2f((ushort_t)vb2[c]);
            acc[c] += wb3 * bf2f((ushort_t)vb3[c]);
        }
    }
}

__global__ __launch_bounds__(256, 3)
void layer_fused(const int* __restrict__ row_start, const int2* __restrict__ perm,
                 const ushort_t* __restrict__ xb, const ushort_t* __restrict__ h0b,
                 const ushort_t* __restrict__ Wt, ushort_t* __restrict__ X,
                 float beta) {
    __shared__ short sS[64][SROW];   // 17.4 KB; wave-private 16-row slices
    int t = threadIdx.x;
    int wave = t >> 6, lane = t & 63;
    int grp = lane >> 4, sl = lane & 15;
    int quad = lane >> 4, l16 = lane & 15;   // gemm aliases
    int row0 = blockIdx.x * 64;
    int G = wave * 4 + grp;                  // block-local group 0..15
    int Rg = row0 + G * 4;                   // 4 rows per group

    // row bounds for this group's 4 rows: one lane-parallel load + shfl
    int rbv = 0;
    if (sl <= 4) {
        int idx = Rg + sl; if (idx > N_NODES) idx = N_NODES;
        rbv = row_start[idx];
    }
    int e0[4], e1[4];
#pragma unroll
    for (int r = 0; r < 4; r++) {
        e0[r] = __shfl(rbv, r, 16);
        e1[r] = __shfl(rbv, r + 1, 16);
    }

    // prefetch row 0's chunk-0 perm entries
    int2 pA = make_int2(0, 0), pB = make_int2(0, 0);
    if (e0[0] + sl < e1[0])      pA = perm[e0[0] + sl];
    if (e0[0] + 16 + sl < e1[0]) pB = perm[e0[0] + 16 + sl];

#pragma unroll
    for (int r = 0; r < 4; r++) {
        int row = Rg + r;

        // issue h0 load early (consumed only at blend)
        short8 h;
#pragma unroll
        for (int c = 0; c < 8; c++) h[c] = 0;
        if (row < N_NODES) h = *(const short8*)(h0b + (size_t)row * HDIM + sl * 8);

        // prefetch next row's perm before touching this row's gathers
        int2 nA = make_int2(0, 0), nB = make_int2(0, 0);
        if (r < 3) {
            if (e0[r + 1] + sl < e1[r + 1])      nA = perm[e0[r + 1] + sl];
            if (e0[r + 1] + 16 + sl < e1[r + 1]) nB = perm[e0[r + 1] + 16 + sl];
        }

        float acc[8];
#pragma unroll
        for (int c = 0; c < 8; c++) acc[c] = 0.f;

        // dynamic trip count: only ceil(min(deg,32)/8)*8 slots touched;
        // slots >= deg carry pm=(0,0) -> w=0, harmless.
        int deg = e1[r] - e0[r];
        int n = deg < 32 ? deg : 32;
        for (int j = 0; j < n; j += 8) {
            int2 pL = (j < 16) ? pA : pB;
            int2 pH = (j + 4 < 16) ? pA : pB;
            int jl = j & 15, jh = (j + 4) & 15;
            int   a0 = __shfl(pL.x, jl + 0, 16), b0 = __shfl(pH.x, jh + 0, 16);
            int   a1 = __shfl(pL.x, jl + 1, 16), b1 = __shfl(pH.x, jh + 1, 16);
            int   a2 = __shfl(pL.x, jl + 2, 16), b2 = __shfl(pH.x, jh + 2, 16);
            int   a3 = __shfl(pL.x, jl + 3, 16), b3 = __shfl(pH.x, jh + 3, 16);
            float wa0 = __int_as_float(__shfl(pL.y, jl + 0, 16));
            float wa1 = __int_as_float(__shfl(pL.y, jl + 1, 16));
            float wa2 = __int_as_float(__shfl(pL.y, jl + 2, 16));
            float wa3 = __int_as_float(__shfl(pL.y, jl + 3, 16));
            float wb0 = __int_as_float(__shfl(pH.y, jh + 0, 16));
            float wb1 = __int_as_float(__shfl(pH.y, jh + 1, 16));
            float wb2 = __int_as_float(__shfl(pH.y, jh + 2, 16));
            float wb3 = __int_as_float(__shfl(pH.y, jh + 3, 16));
            short8 va0 = *(const short8*)(xb + (size_t)a0 * HDIM + sl * 8);
            short8 vb0 = *(const short8*)(xb + (size_t)b0 * HDIM + sl * 8);
            short8 va1 = *(const short8*)(xb + (size_t)a1 * HDIM + sl * 8);
            short8 vb1 = *(const short8*)(xb + (size_t)b1 * HDIM + sl * 8);
            short8 va2 = *(const short8*)(xb + (size_t)a2 * HDIM + sl * 8);
            short8 vb2 = *(const short8*)(xb + (size_t)b2 * HDIM + sl * 8);
            short8 va3 = *(const short8*)(xb + (size_t)a3 * HDIM + sl * 8);
            short8 vb3 = *(const short8*)(xb + (size_t)b3 * HDIM + sl * 8);
#pragma unroll
            for (int c = 0; c < 8; c++) {
                acc[c] += wa0 * bf2f((ushort_t)va0[c]);
                acc[c] += wa1 * bf2f((ushort_t)va1[c]);
                acc[c] += wa2 * bf2f((ushort_t)va2[c]);
                acc[c] += wa3 * bf2f((ushort_t)va3[c]);
                acc[c] += wb0 * bf2f((ushort_t)vb0[c]);
                acc[c] += wb1 * bf2f((ushort_t)vb1[c]);
                acc[c] += wb2 * bf2f((ushort_t)vb2[c]);
                acc[c] += wb3 * bf2f((ushort_t)vb3[c]);
            }
        }

        // rare tails (degree > 32)
        for (int chunk = e0[r] + 32; chunk < e1[r]; chunk += 32) {
            int2 qa = make_int2(0, 0), qb = make_int2(0, 0);
            if (chunk + sl < e1[r])      qa = perm[chunk + sl];
            if (chunk + 16 + sl < e1[r]) qb = perm[chunk + 16 + sl];
            spmm_proc32(qa, qb, xb, sl, acc);
        }

        // blend with h0 and stage to LDS (acc dies here)
        short8 o;
        if (row < N_NODES) {
#pragma unroll
            for (int c = 0; c < 8; c++)
                o[c] = (short)f2bf(0.9f * acc[c] + 0.1f * bf2f((ushort_t)h[c]));
        } else {
#pragma unroll
            for (int c = 0; c < 8; c++) o[c] = 0;
        }
        *(short8*)&sS[G * 4 + r][sl * 8] = o;

        pA = nA; pB = nB;
    }
    // NO __syncthreads(): gemm below consumes only this wave's own sS rows.

    // ---- gemm phase ----
    short8 afrag[4];
#pragma unroll
    for (int ks = 0; ks < 4; ks++)
        afrag[ks] = *(const short8*)&sS[wave * 16 + l16][ks * 32 + quad * 8];

    floatx4 gacc[8];
#pragma unroll
    for (int nt = 0; nt < 8; nt++) {
        const ushort_t* bp = Wt + (size_t)(nt * 16 + l16) * HDIM + quad * 8;
        floatx4 c = (floatx4){0.f, 0.f, 0.f, 0.f};
#pragma unroll
        for (int ks = 0; ks < 4; ks++) {
            short8 b = *(const short8*)(bp + ks * 32);
            c = __builtin_amdgcn_mfma_f32_16x16x32_bf16(afrag[ks], b, c, 0, 0, 0);
        }
        gacc[nt] = c;
    }
    float g = 1.f - beta;
#pragma unroll
    for (int nt = 0; nt < 8; nt++) {
        int col = nt * 16 + l16;
#pragma unroll
        for (int r = 0; r < 4; r++) {
            int lrow = wave * 16 + quad * 4 + r;
            float s = bf2f((ushort_t)sS[lrow][col]);
            float v = beta * gacc[nt][r] + g * s;
            v = v > 0.f ? v : 0.f;
            X[(size_t)(row0 + lrow) * HDIM + col] = f2bf(v);
        }
    }
}

// ---------------- fc1: out = x @ W1 + b1 (fp32 out), N padded 40->48 ----------------

__global__ void fc1_mfma(const ushort_t* __restrict__ X, const ushort_t* __restrict__ Wt1,
                         const float* __restrict__ b1, float* __restrict__ out) {
    int wave = threadIdx.x >> 6;
    int lane = threadIdx.x & 63;
    int quad = lane >> 4, l16 = lane & 15;
    int row0 = blockIdx.x * 64 + wave * 16;

    int arow = row0 + l16; if (arow > N_NODES - 1) arow = N_NODES - 1;
    const ushort_t* ap = X + (size_t)arow * HDIM + quad * 8;
    short8 afrag[4];
#pragma unroll
    for (int ks = 0; ks < 4; ks++) afrag[ks] = *(const short8*)(ap + ks * 32);

    floatx4 acc[3];
#pragma unroll
    for (int nt = 0; nt < 3; nt++) {
        const ushort_t* bp = Wt1 + (size_t)(nt * 16 + l16) * HDIM + quad * 8;
        floatx4 c = (floatx4){0.f, 0.f, 0.f, 0.f};
#pragma unroll
        for (int ks = 0; ks < 4; ks++) {
            short8 b = *(const short8*)(bp + ks * 32);
            c = __builtin_amdgcn_mfma_f32_16x16x32_bf16(afrag[ks], b, c, 0, 0, 0);
        }
        acc[nt] = c;
    }
#pragma unroll
    for (int nt = 0; nt < 3; nt++) {
        int col = nt * 16 + l16;
        if (col < CDIM) {
            float bias = b1[col];
#pragma unroll
            for (int r = 0; r < 4; r++) {
                int row = row0 + quad * 4 + r;
                if (row < N_NODES)
                    out[(size_t)row * CDIM + col] = acc[nt][r] + bias;
            }
        }
    }
}

// ---------------- launch ----------------

extern "C" void kernel_launch(void* const* d_in, const int* in_sizes, int n_in,
                              void* d_out, int out_size, void* d_ws, size_t ws_size,
                              hipStream_t stream) {
    const float* F     = (const float*)d_in[0];
    const int*   ei    = (const int*)d_in[1];
    const float* normA = (const float*)d_in[2];
    const float* W0    = (const float*)d_in[3];
    const float* b0    = (const float*)d_in[4];
    const float* convW = (const float*)d_in[5];
    const float* W1    = (const float*)d_in[6];
    const float* b1    = (const float*)d_in[7];
    float*       out   = (float*)d_out;

    // workspace layout (bf16 trunk), 16B-aligned
    ushort_t* h0b  = (ushort_t*)d_ws;                     // M_PAD*128
    ushort_t* xab  = h0b + (size_t)M_PAD * HDIM;
    ushort_t* xbb  = xab + (size_t)M_PAD * HDIM;
    ushort_t* Wt0  = xbb + (size_t)M_PAD * HDIM;          // 128*512
    ushort_t* WtL  = Wt0 + 128 * 512;                     // 8*128*128
    ushort_t* Wt1  = WtL + 8 * 128 * 128;                 // 48*128
    int*   row_start = (int*)(Wt1 + 48 * 128);
    int*   cursor    = row_start + (N_NODES + 8);
    int*   cnt       = cursor + (N_NODES + 8);
    int*   bsum      = cnt + (N_NODES + 8);
    int*   boff      = bsum + 256;
    int2*  perm      = (int2*)(boff + 256);               // 8B-aligned

    // CSR build
    hipMemsetAsync(cnt, 0, N_NODES * sizeof(int), stream);
    hist_kernel<<<(E_EDGES + 255) / 256, 256, 0, stream>>>(ei + E_EDGES, cnt);
    scanA<<<NB, 256, 0, stream>>>(cnt, bsum);
    scanB<<<1, 256, 0, stream>>>(bsum, boff);
    scanC<<<NB, 256, 0, stream>>>(cnt, boff, row_start, cursor);
    scatter_kernel<<<(E_EDGES + 255) / 256, 256, 0, stream>>>(ei, normA, cursor, perm);
    prep_weights<<<(128 * 512 + 8 * 128 * 128 + 48 * 128 + 255) / 256, 256, 0, stream>>>(
        W0, convW, W1, Wt0, WtL, Wt1);

    fc0_mfma<<<M_PAD / 32, 256, 0, stream>>>(F, Wt0, b0, h0b);

    // after fc0, x == h0: layer 0 reads h0b as both x and h0
    ushort_t* ping = h0b;
    ushort_t* pong = xab;
    for (int i = 0; i < LAYERS; i++) {
        float beta = logf(0.5f / (float)(i + 1) + 1.0f);
        layer_fused<<<M_PAD / 64, 256, 0, stream>>>(
            row_start, perm, ping, h0b, WtL + (size_t)i * HDIM * HDIM, pong, beta);
        if (i == 0) { ping = xab; pong = xbb; }
        else { ushort_t* tmp = ping; ping = pong; pong = tmp; }
    }
    // L0->xab, L1->xbb, ..., L7->xbb; ping == xbb here
    fc1_mfma<<<M_PAD / 64, 256, 0, stream>>>(ping, Wt1, b1, out);
}